// Round 1
// baseline (188.024 us; speedup 1.0000x reference)
//
#include <hip/hip_runtime.h>
#include <math.h>

#define BB 64
#define DD 512
#define HH 8
#define EPS 1e-8f

__global__ __launch_bounds__(256) void flattn_kernel(
    const float* __restrict__ x,
    const float* __restrict__ alphas,
    const float* __restrict__ betas,
    float* __restrict__ out)
{
    const int b = blockIdx.x;
    const int h = blockIdx.y;

    __shared__ float xs[DD];
    __shared__ float vs[DD];

    const float a0 = alphas[h * 3 + 0];
    const float a1 = alphas[h * 3 + 1];
    const float a2 = alphas[h * 3 + 2];
    const float b0 = betas[h * 3 + 0];
    const float b1 = betas[h * 3 + 1];
    const float b2 = betas[h * 3 + 2];

    for (int j = threadIdx.x; j < DD; j += blockDim.x) {
        float xv = x[b * DD + j];
        xs[j] = xv;
        vs[j] = fmaf(a2, xv, b2);
    }
    __syncthreads();

    const float scale = 0.04419417382415922f;       // 1/sqrt(512)
    const float log2e = 1.4426950408889634f;

    for (int i = threadIdx.x; i < DD; i += blockDim.x) {
        const float ki = fmaf(a1, xs[i], b1);
        const float c  = b0 - ki;                   // q_j - k_i = a0*x_j + c

        // Pass 1: min_j |a0*x_j + c|  (max of 1/diff == 1/(min diff + eps))
        float mind = 3.0e38f;
        #pragma unroll 8
        for (int j = 0; j < DD; ++j) {
            float d = fabsf(fmaf(a0, xs[j], c));
            mind = fminf(mind, d);
        }
        const float m = 1.0f / (mind + EPS);        // exact same expr as pass 2

        // Pass 2: softmax-weighted sum of v
        float ssum = 0.0f, svsum = 0.0f;
        #pragma unroll 4
        for (int j = 0; j < DD; ++j) {
            float d = fabsf(fmaf(a0, xs[j], c)) + EPS;
            float r = 1.0f / d;
            float s = __builtin_amdgcn_exp2f((r - m) * log2e);
            ssum  += s;
            svsum  = fmaf(s, vs[j], svsum);
        }

        float att = (svsum / ssum) * scale;
        if (h == 0) att += xs[i];
        atomicAdd(&out[b * DD + i], att);
    }
}

extern "C" void kernel_launch(void* const* d_in, const int* in_sizes, int n_in,
                              void* d_out, int out_size, void* d_ws, size_t ws_size,
                              hipStream_t stream) {
    const float* x      = (const float*)d_in[0];
    const float* alphas = (const float*)d_in[1];
    const float* betas  = (const float*)d_in[2];
    float* out = (float*)d_out;

    hipMemsetAsync(out, 0, (size_t)out_size * sizeof(float), stream);

    dim3 grid(BB, HH);
    dim3 block(256);
    flattn_kernel<<<grid, block, 0, stream>>>(x, alphas, betas, out);
}

// Round 2
// 137.051 us; speedup vs baseline: 1.3719x; 1.3719x over previous
//
#include <hip/hip_runtime.h>
#include <math.h>

#define BB 64
#define DD 512
#define HH 8
#define EPS 1e-8f

// Fast reciprocal: v_rcp_f32 + one Newton-Raphson step (~1 ulp).
// Used identically for the max (m) and the per-j r, so r-m cancels exactly
// at the argmin just like exact division would.
__device__ __forceinline__ float fast_rcp(float d) {
    float r0 = __builtin_amdgcn_rcpf(d);
    float u  = fmaf(-d, r0, 2.0f);
    return r0 * u;
}

__global__ __launch_bounds__(256) void flattn_kernel(
    const float* __restrict__ x,
    const float* __restrict__ alphas,
    const float* __restrict__ betas,
    float* __restrict__ out)
{
    const int b = blockIdx.x;      // batch
    const int ic = blockIdx.y;     // i-chunk (0..1)
    const int h = blockIdx.z;      // head

    __shared__ float xs[DD];
    __shared__ float vs[DD];

    const float a0 = alphas[h * 3 + 0];
    const float a1 = alphas[h * 3 + 1];
    const float a2 = alphas[h * 3 + 2];
    const float b0 = betas[h * 3 + 0];
    const float b1 = betas[h * 3 + 1];
    const float b2 = betas[h * 3 + 2];

    for (int j = threadIdx.x; j < DD; j += blockDim.x) {
        float xv = x[b * DD + j];
        xs[j] = xv;
        vs[j] = fmaf(a2, xv, b2);
    }
    __syncthreads();

    const float scale = 0.04419417382415922f;       // 1/sqrt(512)
    const float log2e = 1.4426950408889634f;

    const int i = ic * 256 + threadIdx.x;           // one i per thread

    const float ki = fmaf(a1, xs[i], b1);
    const float c  = b0 - ki;                       // q_j - k_i = a0*x_j + c

    // Pass 1: min_j |a0*x_j + c|   (fma + min-with-abs-modifier = 2 ops/j)
    float mind = 3.0e38f;
    #pragma unroll 8
    for (int j = 0; j < DD; ++j) {
        float t = fmaf(a0, xs[j], c);
        mind = fminf(mind, fabsf(t));
    }
    const float m = fast_rcp(mind + EPS);           // same expr as pass 2
    const float negmlog = -m * log2e;

    // Pass 2: softmax-weighted sum of v
    float ssum = 0.0f, svsum = 0.0f;
    #pragma unroll 4
    for (int j = 0; j < DD; ++j) {
        float t = fmaf(a0, xs[j], c);
        float d = fabsf(t) + EPS;
        float r = fast_rcp(d);
        float s = __builtin_amdgcn_exp2f(fmaf(r, log2e, negmlog));
        ssum  += s;
        svsum  = fmaf(s, vs[j], svsum);
    }

    float att = (svsum / ssum) * scale;
    if (h == 0) att += xs[i];
    atomicAdd(&out[b * DD + i], att);
}

extern "C" void kernel_launch(void* const* d_in, const int* in_sizes, int n_in,
                              void* d_out, int out_size, void* d_ws, size_t ws_size,
                              hipStream_t stream) {
    const float* x      = (const float*)d_in[0];
    const float* alphas = (const float*)d_in[1];
    const float* betas  = (const float*)d_in[2];
    float* out = (float*)d_out;

    hipMemsetAsync(out, 0, (size_t)out_size * sizeof(float), stream);

    dim3 grid(BB, 2, HH);
    dim3 block(256);
    flattn_kernel<<<grid, block, 0, stream>>>(x, alphas, betas, out);
}